// Round 2
// baseline (167.710 us; speedup 1.0000x reference)
//
#include <hip/hip_runtime.h>
#include <math.h>

// ARAP loss: out[b] = mean_e | ||x[b,k]-x[b,j]||^2 - ||dx[b,k]-dx[b,j]||^2 |
//
// Strategy:
//  1. transpose+fuse x,dx (B,NV,3) -> ct (NV,B,6): per (vertex,batch) a 24B
//     record {x.xyz, dx.xyz}. The 16 batch records of one vertex form one
//     contiguous 384B segment.
//  2. main kernel maps b = tid&15 so each 16-lane group shares one edge ->
//     every endpoint gather is one coalesced 384B segment, 2 dwordx3/lane
//     from a single address. Inputs (38.4MB) are L3-resident -> gather hits L2/L3.
//  3. shfl-fold reduction to 16 per-batch partials per block, double-precision
//     finalize kernel computes the mean. No atomics.

#define THREADS 256
#define NBLOCKS 2048   // 256 CUs x 8 blocks, grid-stride over edge slots

// ---------- transpose+fuse (B,NV,3) x2 -> (NV,B,6) ----------
__global__ void arap_transpose(const float* __restrict__ x,
                               const float* __restrict__ dx,
                               float* __restrict__ ct,
                               int NV, int B) {
    // tile[v][b*6+c]; row padded 96->99 floats (96%32==0 was a 16-way conflict)
    __shared__ float tile[16][99];
    int t  = threadIdx.x;               // 256 threads
    int v0 = blockIdx.x << 4;           // 16 vertices per block
    int bb = t >> 4;                    // phase-1: batch
    int vv = t & 15;                    // phase-1: vertex (fast dim -> coalesced read)
    if (v0 + vv < NV) {
        size_t src = ((size_t)bb * NV + (v0 + vv)) * 3;
        #pragma unroll
        for (int c = 0; c < 3; ++c) {
            tile[vv][bb * 6 + c]     = x[src + c];
            tile[vv][bb * 6 + 3 + c] = dx[src + c];
        }
    }
    __syncthreads();
    int vv2 = t >> 4;                   // phase-2: vertex
    int bb2 = t & 15;                   // phase-2: batch (fast dim -> coalesced write)
    if (v0 + vv2 < NV) {
        size_t dst = ((size_t)(v0 + vv2) * B + bb2) * 6;
        #pragma unroll
        for (int c = 0; c < 6; ++c)
            ct[dst + c] = tile[vv2][bb2 * 6 + c];
    }
}

// ---------- main gather + per-block reduce (fused ct layout) ----------
__global__ void arap_main_fused(const float* __restrict__ ct,
                                const int2* __restrict__ edges,
                                float* __restrict__ partial,
                                int E, int B) {
    int t    = threadIdx.x;
    int b    = t & 15;                               // batch lane
    int slot = (blockIdx.x * blockDim.x + t) >> 4;   // edge slot
    int nslots = (gridDim.x * blockDim.x) >> 4;
    int boff = b * 6;
    int svB  = B * 6;                                // 96 floats per vertex
    float acc = 0.f;
    for (int e = slot; e < E; e += nslots) {
        int2 jk = edges[e];                          // same addr across group -> broadcast
        const float* pj = ct + (jk.x * svB + boff);
        const float* pk = ct + (jk.y * svB + boff);
        float xjx = pj[0], xjy = pj[1], xjz = pj[2];
        float djx = pj[3], djy = pj[4], djz = pj[5];
        float xkx = pk[0], xky = pk[1], xkz = pk[2];
        float dkx = pk[3], dky = pk[4], dkz = pk[5];
        float ex = xkx - xjx, ey = xky - xjy, ez = xkz - xjz;
        float fx = dkx - djx, fy = dky - djy, fz = dkz - djz;
        float sq  = ex * ex + ey * ey + ez * ez;
        float dsq = fx * fx + fy * fy + fz * fz;
        acc += fabsf(sq - dsq);
    }
    // fold the 4 edge-slots of this wave onto lanes 0-15 (one lane per b)
    acc += __shfl_xor(acc, 16, 64);
    acc += __shfl_xor(acc, 32, 64);
    __shared__ float sacc[THREADS / 64][16];
    int wave = t >> 6, lane = t & 63;
    if (lane < 16) sacc[wave][lane] = acc;
    __syncthreads();
    if (t < 16) {
        float s = 0.f;
        #pragma unroll
        for (int w = 0; w < THREADS / 64; ++w) s += sacc[w][t];
        partial[(size_t)blockIdx.x * 16 + t] = s;   // every block writes -> no memset needed
    }
}

// ---------- fallback: gather directly from (B,NV,3) arrays ----------
__global__ void arap_main_generic(const float* __restrict__ X,
                                  const float* __restrict__ DX,
                                  const int2* __restrict__ edges,
                                  float* __restrict__ partial,
                                  int E, int B, int sv, int sb) {
    int t    = threadIdx.x;
    int b    = t & 15;
    int slot = (blockIdx.x * blockDim.x + t) >> 4;
    int nslots = (gridDim.x * blockDim.x) >> 4;
    int boff = b * sb;
    float acc = 0.f;
    for (int e = slot; e < E; e += nslots) {
        int2 jk = edges[e];
        int aj = jk.x * sv + boff;
        int ak = jk.y * sv + boff;
        float ex = X[ak] - X[aj], ey = X[ak + 1] - X[aj + 1], ez = X[ak + 2] - X[aj + 2];
        float fx = DX[ak] - DX[aj], fy = DX[ak + 1] - DX[aj + 1], fz = DX[ak + 2] - DX[aj + 2];
        acc += fabsf((ex * ex + ey * ey + ez * ez) - (fx * fx + fy * fy + fz * fz));
    }
    acc += __shfl_xor(acc, 16, 64);
    acc += __shfl_xor(acc, 32, 64);
    __shared__ float sacc[THREADS / 64][16];
    int wave = t >> 6, lane = t & 63;
    if (lane < 16) sacc[wave][lane] = acc;
    __syncthreads();
    if (t < 16) {
        float s = 0.f;
        #pragma unroll
        for (int w = 0; w < THREADS / 64; ++w) s += sacc[w][t];
        partial[(size_t)blockIdx.x * 16 + t] = s;
    }
}

// ---------- finalize: reduce NB partials per batch in double, write mean ----------
__global__ void arap_finalize(const float* __restrict__ partial,
                              float* __restrict__ out, int NB, double invE) {
    int b = blockIdx.x;          // one block per batch
    int t = threadIdx.x;         // 256 threads
    double s = 0.0;
    for (int i = t; i < NB; i += blockDim.x)
        s += (double)partial[(size_t)i * 16 + b];
    #pragma unroll
    for (int off = 32; off; off >>= 1) s += __shfl_xor(s, off, 64);
    __shared__ double ws_[THREADS / 64];
    int wave = t >> 6, lane = t & 63;
    if (lane == 0) ws_[wave] = s;
    __syncthreads();
    if (t == 0) {
        double tot = 0.0;
        #pragma unroll
        for (int w = 0; w < THREADS / 64; ++w) tot += ws_[w];
        out[b] = (float)(tot * invE);
    }
}

extern "C" void kernel_launch(void* const* d_in, const int* in_sizes, int n_in,
                              void* d_out, int out_size, void* d_ws, size_t ws_size,
                              hipStream_t stream) {
    const float* dx    = (const float*)d_in[0];   // (B, NV, 3)
    const float* x     = (const float*)d_in[1];   // (B, NV, 3)
    const int*   edges = (const int*)d_in[2];     // (E, 2)
    float* out = (float*)d_out;

    int B  = out_size;                 // 16
    int E  = in_sizes[2] / 2;          // ~1.2M directed edges
    int NV = in_sizes[0] / (B * 3);    // 100000

    size_t partial_bytes = ((size_t)NBLOCKS * 16 * sizeof(float) + 255) & ~(size_t)255;
    size_t ct_bytes      = (size_t)NV * B * 6 * sizeof(float);

    float* partial = (float*)d_ws;

    if (ws_size >= partial_bytes + ct_bytes) {
        float* ct = (float*)((char*)d_ws + partial_bytes);
        int tgrid = (NV + 15) / 16;
        arap_transpose<<<tgrid, 256, 0, stream>>>(x, dx, ct, NV, B);
        arap_main_fused<<<NBLOCKS, THREADS, 0, stream>>>(ct, (const int2*)edges,
                                                         partial, E, B);
    } else {
        arap_main_generic<<<NBLOCKS, THREADS, 0, stream>>>(x, dx, (const int2*)edges,
                                                           partial, E, B, 3, NV * 3);
    }
    arap_finalize<<<B, THREADS, 0, stream>>>(partial, out, NBLOCKS, 1.0 / (double)E);
}

// Round 3
// 166.879 us; speedup vs baseline: 1.0050x; 1.0050x over previous
//
#include <hip/hip_runtime.h>
#include <math.h>

// ARAP loss: out[b] = mean_e | ||x[b,k]-x[b,j]||^2 - ||dx[b,k]-dx[b,j]||^2 |
//
//  1. transpose+fuse x,dx (B,NV,3) -> ct (NV,B,6): 24B record {x.xyz,dx.xyz};
//     the 16 batch records of one vertex form one contiguous 384B segment.
//  2. main kernel: b = tid&15, 16-lane group shares one edge. Edge list is
//     sorted by j (np.unique) and symmetric ((j,k) <-> (k,j) contribute
//     identical f32 values), so: process only j<k with weight 2, and give
//     each group a CONTIGUOUS edge chunk + XCD-swizzle blocks so each XCD's
//     j-working-set (~4.8MB) fits its 4MiB L2. k-side stays random.
//  3. shfl-fold to 16 per-batch partials per block; double-precision finalize.

#define THREADS 256
#define NBLOCKS 2048            // 8 blocks/CU, all resident
#define GROUPS_PER_BLOCK (THREADS / 16)
#define NGROUPS (NBLOCKS * GROUPS_PER_BLOCK)
#define TV 64                   // vertices per transpose block

// ---------- transpose+fuse (B,NV,3) x2 -> (NV,B,6) ----------
__global__ void arap_transpose(const float* __restrict__ x,
                               const float* __restrict__ dx,
                               float* __restrict__ ct,
                               int NV, int B) {
    __shared__ float tile[TV][99];     // row 99: stride-3 banks, conflict-free
    int t  = threadIdx.x;
    int v0 = blockIdx.x * TV;
    int bb = t >> 4;                   // phase-1: batch (group-uniform)
    int vb = t & 15;                   // phase-1: vertex (fast -> coalesced 192B)
    #pragma unroll
    for (int vi = 0; vi < TV / 16; ++vi) {
        int v = v0 + vi * 16 + vb;
        if (v < NV) {
            size_t sx = ((size_t)bb * NV + v) * 3;
            #pragma unroll
            for (int c = 0; c < 3; ++c) {
                tile[vi * 16 + vb][bb * 6 + c]     = x[sx + c];
                tile[vi * 16 + vb][bb * 6 + 3 + c] = dx[sx + c];
            }
        }
    }
    __syncthreads();
    int vg = t >> 4;                   // phase-2: vertex row
    int b2 = t & 15;                   // phase-2: batch (fast -> contiguous 384B)
    #pragma unroll
    for (int vi = 0; vi < TV / 16; ++vi) {
        int vv = vi * 16 + vg;
        int v  = v0 + vv;
        if (v < NV) {
            float2 a0 = make_float2(tile[vv][b2 * 6 + 0], tile[vv][b2 * 6 + 1]);
            float2 a1 = make_float2(tile[vv][b2 * 6 + 2], tile[vv][b2 * 6 + 3]);
            float2 a2 = make_float2(tile[vv][b2 * 6 + 4], tile[vv][b2 * 6 + 5]);
            float2* dst = (float2*)(ct + ((size_t)v * B + b2) * 6);  // 24B-aligned
            dst[0] = a0; dst[1] = a1; dst[2] = a2;
        }
    }
}

// ---------- main gather: contiguous chunks, j<k only ----------
__global__ void arap_main_fused(const float* __restrict__ ct,
                                const int2* __restrict__ edges,
                                float* __restrict__ partial,
                                int E, int chunk) {
    int t   = threadIdx.x;
    int b   = t & 15;
    // XCD swizzle: XCD n (bid%8) gets blocks covering the n-th contiguous
    // eighth of the edge list -> per-XCD j-range ~NV/8 -> ~4.8MB, L2-fits.
    int sbid = (blockIdx.x & 7) * (NBLOCKS >> 3) + (blockIdx.x >> 3);
    int g    = sbid * GROUPS_PER_BLOCK + (t >> 4);
    long e0 = (long)g * chunk;
    long e1 = e0 + chunk; if (e1 > E) e1 = E;
    const float* base = ct + b * 6;
    float acc = 0.f;
    for (long e = e0; e < e1; ++e) {
        int2 jk = edges[e];            // broadcast across the 16-lane group
        if (jk.x < jk.y) {             // mirror edge (k,j) is bit-identical
            const float* pj = base + (size_t)jk.x * 96;
            const float* pk = base + (size_t)jk.y * 96;
            float xjx = pj[0], xjy = pj[1], xjz = pj[2];
            float djx = pj[3], djy = pj[4], djz = pj[5];
            float xkx = pk[0], xky = pk[1], xkz = pk[2];
            float dkx = pk[3], dky = pk[4], dkz = pk[5];
            float ex = xkx - xjx, ey = xky - xjy, ez = xkz - xjz;
            float fx = dkx - djx, fy = dky - djy, fz = dkz - djz;
            float sq  = ex * ex + ey * ey + ez * ez;
            float dsq = fx * fx + fy * fy + fz * fz;
            acc += fabsf(sq - dsq);
        }
    }
    // fold the 4 edge-slots of this wave onto lanes 0-15 (one lane per b)
    acc += __shfl_xor(acc, 16, 64);
    acc += __shfl_xor(acc, 32, 64);
    __shared__ float sacc[THREADS / 64][16];
    int wave = t >> 6, lane = t & 63;
    if (lane < 16) sacc[wave][lane] = acc;
    __syncthreads();
    if (t < 16) {
        float s = 0.f;
        #pragma unroll
        for (int w = 0; w < THREADS / 64; ++w) s += sacc[w][t];
        partial[(size_t)blockIdx.x * 16 + t] = s;   // every block writes
    }
}

// ---------- fallback: direct gather from (B,NV,3), same j<k trick ----------
__global__ void arap_main_generic(const float* __restrict__ X,
                                  const float* __restrict__ DX,
                                  const int2* __restrict__ edges,
                                  float* __restrict__ partial,
                                  int E, int chunk, int NV) {
    int t = threadIdx.x;
    int b = t & 15;
    int sbid = (blockIdx.x & 7) * (NBLOCKS >> 3) + (blockIdx.x >> 3);
    int g    = sbid * GROUPS_PER_BLOCK + (t >> 4);
    long e0 = (long)g * chunk;
    long e1 = e0 + chunk; if (e1 > E) e1 = E;
    size_t boff = (size_t)b * NV * 3;
    float acc = 0.f;
    for (long e = e0; e < e1; ++e) {
        int2 jk = edges[e];
        if (jk.x < jk.y) {
            size_t aj = boff + (size_t)jk.x * 3, ak = boff + (size_t)jk.y * 3;
            float ex = X[ak] - X[aj], ey = X[ak+1] - X[aj+1], ez = X[ak+2] - X[aj+2];
            float fx = DX[ak] - DX[aj], fy = DX[ak+1] - DX[aj+1], fz = DX[ak+2] - DX[aj+2];
            acc += fabsf((ex*ex + ey*ey + ez*ez) - (fx*fx + fy*fy + fz*fz));
        }
    }
    acc += __shfl_xor(acc, 16, 64);
    acc += __shfl_xor(acc, 32, 64);
    __shared__ float sacc[THREADS / 64][16];
    int wave = t >> 6, lane = t & 63;
    if (lane < 16) sacc[wave][lane] = acc;
    __syncthreads();
    if (t < 16) {
        float s = 0.f;
        #pragma unroll
        for (int w = 0; w < THREADS / 64; ++w) s += sacc[w][t];
        partial[(size_t)blockIdx.x * 16 + t] = s;
    }
}

// ---------- finalize: reduce per-block partials in double, write mean ----------
__global__ void arap_finalize(const float* __restrict__ partial,
                              float* __restrict__ out, int NB, double scale) {
    int b = blockIdx.x;
    int t = threadIdx.x;
    double s = 0.0;
    for (int i = t; i < NB; i += blockDim.x)
        s += (double)partial[(size_t)i * 16 + b];
    #pragma unroll
    for (int off = 32; off; off >>= 1) s += __shfl_xor(s, off, 64);
    __shared__ double ws_[THREADS / 64];
    int wave = t >> 6, lane = t & 63;
    if (lane == 0) ws_[wave] = s;
    __syncthreads();
    if (t == 0) {
        double tot = 0.0;
        #pragma unroll
        for (int w = 0; w < THREADS / 64; ++w) tot += ws_[w];
        out[b] = (float)(tot * scale);
    }
}

extern "C" void kernel_launch(void* const* d_in, const int* in_sizes, int n_in,
                              void* d_out, int out_size, void* d_ws, size_t ws_size,
                              hipStream_t stream) {
    const float* dx    = (const float*)d_in[0];   // (B, NV, 3)
    const float* x     = (const float*)d_in[1];   // (B, NV, 3)
    const int*   edges = (const int*)d_in[2];     // (E, 2), sorted, symmetric
    float* out = (float*)d_out;

    int B  = out_size;                 // 16
    int E  = in_sizes[2] / 2;
    int NV = in_sizes[0] / (B * 3);    // 100000

    int chunk = (E + NGROUPS - 1) / NGROUPS;

    size_t partial_bytes = ((size_t)NBLOCKS * 16 * sizeof(float) + 255) & ~(size_t)255;
    size_t ct_bytes      = (size_t)NV * B * 6 * sizeof(float);

    float* partial = (float*)d_ws;
    // weight 2: only j<k edges were accumulated; mirrors are bit-identical.
    double scale = 2.0 / (double)E;

    if (ws_size >= partial_bytes + ct_bytes) {
        float* ct = (float*)((char*)d_ws + partial_bytes);
        arap_transpose<<<(NV + TV - 1) / TV, THREADS, 0, stream>>>(x, dx, ct, NV, B);
        arap_main_fused<<<NBLOCKS, THREADS, 0, stream>>>(ct, (const int2*)edges,
                                                         partial, E, chunk);
    } else {
        arap_main_generic<<<NBLOCKS, THREADS, 0, stream>>>(x, dx, (const int2*)edges,
                                                           partial, E, chunk, NV);
    }
    arap_finalize<<<B, THREADS, 0, stream>>>(partial, out, NBLOCKS, scale);
}

// Round 4
// 155.403 us; speedup vs baseline: 1.0792x; 1.0738x over previous
//
#include <hip/hip_runtime.h>
#include <math.h>

// ARAP loss: out[b] = mean_e | ||x[b,k]-x[b,j]||^2 - ||dx[b,k]-dx[b,j]||^2 |
//
//  1. transpose+fuse x,dx (B,NV,3) -> ct (NV,B,6): 24B record {x.xyz,dx.xyz};
//     16 batch records of a vertex = one contiguous 384B segment.
//  2. main kernel, per 64-lane wave: take a 128-edge window, ballot-compact
//     the j<k survivors (mirror edges are bit-identical -> weight 2) into a
//     per-wave LDS buffer, then each 16-lane group (lane b = t&15) walks its
//     share BRANCHLESSLY 4 edges at a time -> ~24 independent dwordx2 gathers
//     in flight per lane (was: 1 dependent chain inside a divergent branch).
//  3. shfl-fold to 16 per-batch partials per block; double-precision finalize.

#define THREADS 256
#define TV 64                   // vertices per transpose block
#define WEDGES 128              // edges per wave window
#define BEDGES (WEDGES * 4)     // edges per block (4 waves)
#define GENBLOCKS 2048          // fallback grid

// ---------- transpose+fuse (B,NV,3) x2 -> (NV,B,6) ----------
__global__ void arap_transpose(const float* __restrict__ x,
                               const float* __restrict__ dx,
                               float* __restrict__ ct,
                               int NV, int B) {
    __shared__ float tile[TV][99];
    int t  = threadIdx.x;
    int v0 = blockIdx.x * TV;
    int bb = t >> 4;
    int vb = t & 15;
    #pragma unroll
    for (int vi = 0; vi < TV / 16; ++vi) {
        int v = v0 + vi * 16 + vb;
        if (v < NV) {
            size_t sx = ((size_t)bb * NV + v) * 3;
            #pragma unroll
            for (int c = 0; c < 3; ++c) {
                tile[vi * 16 + vb][bb * 6 + c]     = x[sx + c];
                tile[vi * 16 + vb][bb * 6 + 3 + c] = dx[sx + c];
            }
        }
    }
    __syncthreads();
    int vg = t >> 4;
    int b2 = t & 15;
    #pragma unroll
    for (int vi = 0; vi < TV / 16; ++vi) {
        int vv = vi * 16 + vg;
        int v  = v0 + vv;
        if (v < NV) {
            float2 a0 = make_float2(tile[vv][b2 * 6 + 0], tile[vv][b2 * 6 + 1]);
            float2 a1 = make_float2(tile[vv][b2 * 6 + 2], tile[vv][b2 * 6 + 3]);
            float2 a2 = make_float2(tile[vv][b2 * 6 + 4], tile[vv][b2 * 6 + 5]);
            float2* dst = (float2*)(ct + ((size_t)v * B + b2) * 6);
            dst[0] = a0; dst[1] = a1; dst[2] = a2;
        }
    }
}

// 24B record load: three 8B-aligned float2
#define LOAD6(v, A0, A1, A2) { \
    const float2* _p = (const float2*)(vbase + (size_t)(v) * 96); \
    A0 = _p[0]; A1 = _p[1]; A2 = _p[2]; }

// diff from two records (j: J0..J2, k: K0..K2); x=(J0.x,J0.y,J1.x) dx=(J1.y,J2.x,J2.y)
#define EV(J0, J1, J2, K0, K1, K2) ({ \
    float _ex = K0.x - J0.x, _ey = K0.y - J0.y, _ez = K1.x - J1.x; \
    float _fx = K1.y - J1.y, _fy = K2.x - J2.x, _fz = K2.y - J2.y; \
    fabsf((_ex*_ex + _ey*_ey + _ez*_ez) - (_fx*_fx + _fy*_fy + _fz*_fz)); })

// ---------- main: wave-compacted branchless gather ----------
__global__ void arap_main_fused(const float* __restrict__ ct,
                                const int2* __restrict__ edges,
                                float* __restrict__ partial,
                                long E, int grid8) {
    int t    = threadIdx.x;
    int lane = t & 63;
    int wv   = t >> 6;           // wave in block
    int b    = t & 15;           // batch lane
    int sg   = (t >> 4) & 3;     // 16-lane group within wave

    __shared__ int2  cbuf[4][WEDGES];
    __shared__ float sacc[4][16];

    // XCD swizzle: each XCD owns a contiguous 1/8 of the edge list
    int sbid = (blockIdx.x & 7) * (grid8 >> 3) + (blockIdx.x >> 3);
    long base_e = ((long)sbid * 4 + wv) * WEDGES;

    // --- load 2 edges/lane, predicate j<k, deterministic rank-compact ---
    long eidx = base_e + 2 * lane;
    int4 q = make_int4(0, 0, 0, 0);
    if (eidx + 1 < E)      q = *(const int4*)(&edges[eidx]);   // 16B aligned
    else if (eidx < E)   { int2 e2 = edges[eidx]; q.x = e2.x; q.y = e2.y; }
    bool p0 = q.x < q.y;
    bool p1 = q.z < q.w;
    unsigned long long m0 = __ballot(p0);
    unsigned long long m1 = __ballot(p1);
    unsigned long long pre = ((unsigned long long)1 << lane) - 1;
    int n0    = __popcll(m0);
    int npass = n0 + __popcll(m1);
    if (p0) cbuf[wv][__popcll(m0 & pre)]      = make_int2(q.x, q.y);
    if (p1) cbuf[wv][n0 + __popcll(m1 & pre)] = make_int2(q.z, q.w);
    __syncthreads();

    // --- branchless gather: group sg takes compacted indices sg, sg+4, ... ---
    const float* vbase = ct + b * 6;
    float acc = 0.f;
    int i = sg;
    for (; i + 12 < npass; i += 16) {            // 4-edge MLP batch
        int2 E0 = cbuf[wv][i], E1 = cbuf[wv][i + 4];
        int2 E2 = cbuf[wv][i + 8], E3 = cbuf[wv][i + 12];
        float2 a0,a1,a2, b0,b1,b2, c0,c1,c2, d0,d1,d2;
        float2 e0,e1,e2, f0,f1,f2, g0,g1,g2, h0,h1,h2;
        LOAD6(E0.x, a0,a1,a2)  LOAD6(E0.y, b0,b1,b2)
        LOAD6(E1.x, c0,c1,c2)  LOAD6(E1.y, d0,d1,d2)
        LOAD6(E2.x, e0,e1,e2)  LOAD6(E2.y, f0,f1,f2)
        LOAD6(E3.x, g0,g1,g2)  LOAD6(E3.y, h0,h1,h2)
        float v0 = EV(a0,a1,a2, b0,b1,b2);
        float v1 = EV(c0,c1,c2, d0,d1,d2);
        float v2 = EV(e0,e1,e2, f0,f1,f2);
        float v3 = EV(g0,g1,g2, h0,h1,h2);
        acc += (v0 + v1) + (v2 + v3);
    }
    for (; i + 4 < npass; i += 8) {              // 2-edge batch
        int2 E0 = cbuf[wv][i], E1 = cbuf[wv][i + 4];
        float2 a0,a1,a2, b0,b1,b2, c0,c1,c2, d0,d1,d2;
        LOAD6(E0.x, a0,a1,a2)  LOAD6(E0.y, b0,b1,b2)
        LOAD6(E1.x, c0,c1,c2)  LOAD6(E1.y, d0,d1,d2)
        acc += EV(a0,a1,a2, b0,b1,b2) + EV(c0,c1,c2, d0,d1,d2);
    }
    for (; i < npass; i += 4) {                  // single
        int2 E0 = cbuf[wv][i];
        float2 a0,a1,a2, b0,b1,b2;
        LOAD6(E0.x, a0,a1,a2)  LOAD6(E0.y, b0,b1,b2)
        acc += EV(a0,a1,a2, b0,b1,b2);
    }

    // fold 4 edge-slots of the wave onto lanes 0-15 (one per b)
    acc += __shfl_xor(acc, 16, 64);
    acc += __shfl_xor(acc, 32, 64);
    if (lane < 16) sacc[wv][lane] = acc;
    __syncthreads();
    if (t < 16) {
        float s = 0.f;
        #pragma unroll
        for (int w = 0; w < 4; ++w) s += sacc[w][t];
        partial[(size_t)blockIdx.x * 16 + t] = s;
    }
}

// ---------- fallback: direct gather from (B,NV,3), j<k, chunked ----------
__global__ void arap_main_generic(const float* __restrict__ X,
                                  const float* __restrict__ DX,
                                  const int2* __restrict__ edges,
                                  float* __restrict__ partial,
                                  long E, int chunk, int NV, int B) {
    int t = threadIdx.x;
    int b = t & 15;
    int g = blockIdx.x * (THREADS / 16) + (t >> 4);
    long e0 = (long)g * chunk;
    long e1 = e0 + chunk; if (e1 > E) e1 = E;
    size_t boff = (size_t)b * NV * 3;
    float acc = 0.f;
    if (b < B) {
        for (long e = e0; e < e1; ++e) {
            int2 jk = edges[e];
            if (jk.x < jk.y) {
                size_t aj = boff + (size_t)jk.x * 3, ak = boff + (size_t)jk.y * 3;
                float ex = X[ak] - X[aj], ey = X[ak+1] - X[aj+1], ez = X[ak+2] - X[aj+2];
                float fx = DX[ak] - DX[aj], fy = DX[ak+1] - DX[aj+1], fz = DX[ak+2] - DX[aj+2];
                acc += fabsf((ex*ex + ey*ey + ez*ez) - (fx*fx + fy*fy + fz*fz));
            }
        }
    }
    acc += __shfl_xor(acc, 16, 64);
    acc += __shfl_xor(acc, 32, 64);
    __shared__ float sacc[THREADS / 64][16];
    int wave = t >> 6, lane = t & 63;
    if (lane < 16) sacc[wave][lane] = acc;
    __syncthreads();
    if (t < 16) {
        float s = 0.f;
        #pragma unroll
        for (int w = 0; w < THREADS / 64; ++w) s += sacc[w][t];
        partial[(size_t)blockIdx.x * 16 + t] = s;
    }
}

// ---------- finalize: reduce per-block partials in double, write mean ----------
__global__ void arap_finalize(const float* __restrict__ partial,
                              float* __restrict__ out, int NB, double scale) {
    int b = blockIdx.x;
    int t = threadIdx.x;
    double s = 0.0;
    for (int i = t; i < NB; i += blockDim.x)
        s += (double)partial[(size_t)i * 16 + b];
    #pragma unroll
    for (int off = 32; off; off >>= 1) s += __shfl_xor(s, off, 64);
    __shared__ double ws_[THREADS / 64];
    int wave = t >> 6, lane = t & 63;
    if (lane == 0) ws_[wave] = s;
    __syncthreads();
    if (t == 0) {
        double tot = 0.0;
        #pragma unroll
        for (int w = 0; w < THREADS / 64; ++w) tot += ws_[w];
        out[b] = (float)(tot * scale);
    }
}

extern "C" void kernel_launch(void* const* d_in, const int* in_sizes, int n_in,
                              void* d_out, int out_size, void* d_ws, size_t ws_size,
                              hipStream_t stream) {
    const float* dx    = (const float*)d_in[0];   // (B, NV, 3)
    const float* x     = (const float*)d_in[1];   // (B, NV, 3)
    const int*   edges = (const int*)d_in[2];     // (E, 2), sorted, symmetric
    float* out = (float*)d_out;

    int B   = out_size;                 // 16
    long E  = in_sizes[2] / 2;
    int NV  = in_sizes[0] / (B * 3);    // 100000

    // fused grid: one 128-edge window per wave, rounded to multiple of 8 blocks
    int gridE = (int)((E + BEDGES - 1) / BEDGES);
    int grid8 = ((gridE + 7) / 8) * 8;

    size_t partial_bytes = ((size_t)grid8 * 16 * sizeof(float) + 255) & ~(size_t)255;
    size_t ct_bytes      = (size_t)NV * B * 6 * sizeof(float);

    float* partial = (float*)d_ws;
    double scale = 2.0 / (double)E;     // j<k only; mirrors are bit-identical

    if (B == 16 && ws_size >= partial_bytes + ct_bytes) {
        float* ct = (float*)((char*)d_ws + partial_bytes);
        arap_transpose<<<(NV + TV - 1) / TV, THREADS, 0, stream>>>(x, dx, ct, NV, B);
        arap_main_fused<<<grid8, THREADS, 0, stream>>>(ct, (const int2*)edges,
                                                       partial, E, grid8);
        arap_finalize<<<B, THREADS, 0, stream>>>(partial, out, grid8, scale);
    } else {
        int ggrid = GENBLOCKS;
        int chunk = (int)((E + (long)ggrid * 16 - 1) / ((long)ggrid * 16));
        arap_main_generic<<<ggrid, THREADS, 0, stream>>>(x, dx, (const int2*)edges,
                                                         partial, E, chunk, NV, B);
        arap_finalize<<<B, THREADS, 0, stream>>>(partial, out, ggrid, scale);
    }
}